// Round 1
// baseline (3194.581 us; speedup 1.0000x reference)
//
#include <hip/hip_runtime.h>

#define N_NODES 100000
#define N_EDGES 1600000
#define IN_F 256
#define OUT_F 128

// out[i, :] = b[:]  (must init every call; harness poisons d_out with 0xAA)
__global__ __launch_bounds__(256) void init_out_kernel(float* __restrict__ out,
                                                       const float* __restrict__ b) {
    int i = blockIdx.x * 256 + threadIdx.x;        // over N_NODES*OUT_F/4 float4s
    const int total4 = N_NODES * OUT_F / 4;
    if (i < total4) {
        float4* out4 = (float4*)out;
        const float4* b4 = (const float4*)b;
        out4[i] = b4[i & 31];                      // OUT_F/4 == 32
    }
}

// h = x @ w : [N,256] @ [256,128] -> [N,128]
// Block: 256 threads = 8 rows x 32 col-quads. x rows staged in LDS (8 KB).
// w rows read via L1/L2 (w = 128 KB, fully L2-resident after first touch).
__global__ __launch_bounds__(256) void gemm_kernel(const float* __restrict__ x,
                                                   const float* __restrict__ w,
                                                   float* __restrict__ h) {
    __shared__ float xs[8][IN_F];                  // 8 KB
    const int block_row = blockIdx.x * 8;
    const int t = threadIdx.x;

    // Stage 8 rows of x (2048 floats = 512 float4) cooperatively.
    const int nrows = min(8, N_NODES - block_row);
    const int valid4 = nrows * (IN_F / 4);
    const float4* x4 = (const float4*)(x + (long long)block_row * IN_F);
    float4* xs4 = (float4*)&xs[0][0];
    for (int idx = t; idx < 512; idx += 256) {
        if (idx < valid4) xs4[idx] = x4[idx];
    }
    __syncthreads();

    const int r  = t >> 5;                         // 0..7
    const int c4 = t & 31;                         // 0..31 (float4 column index)
    float4 acc = make_float4(0.f, 0.f, 0.f, 0.f);
    const float4* w4 = (const float4*)w;           // row k = 32 float4s
    #pragma unroll 8
    for (int k = 0; k < IN_F; ++k) {
        const float xv = xs[r][k];
        const float4 wv = w4[k * 32 + c4];
        acc.x += xv * wv.x;
        acc.y += xv * wv.y;
        acc.z += xv * wv.z;
        acc.w += xv * wv.w;
    }
    const int row = block_row + r;
    if (row < N_NODES) {
        float4* h4 = (float4*)h;
        h4[(long long)row * 32 + c4] = acc;
    }
}

// out[dst] += weight * h[src], 32 threads per edge (float4 per thread).
__global__ __launch_bounds__(256) void scatter_kernel(const float* __restrict__ h,
                                                      const int* __restrict__ edge_src,
                                                      const int* __restrict__ edge_dst,
                                                      const float* __restrict__ edge_weight,
                                                      float* __restrict__ out) {
    const int gtid = blockIdx.x * 256 + threadIdx.x;   // < 51.2M, fits int32
    const int e = gtid >> 5;
    const int j = gtid & 31;
    if (e < N_EDGES) {
        const int   src = edge_src[e];
        const int   dst = edge_dst[e];
        const float wgt = edge_weight[e];
        const float4* h4 = (const float4*)h;
        const float4 hv = h4[(long long)src * 32 + j];
        float* op = out + (long long)dst * OUT_F + j * 4;
        atomicAdd(op + 0, hv.x * wgt);
        atomicAdd(op + 1, hv.y * wgt);
        atomicAdd(op + 2, hv.z * wgt);
        atomicAdd(op + 3, hv.w * wgt);
    }
}

extern "C" void kernel_launch(void* const* d_in, const int* in_sizes, int n_in,
                              void* d_out, int out_size, void* d_ws, size_t ws_size,
                              hipStream_t stream) {
    const float* x           = (const float*)d_in[0];
    const int*   edge_src    = (const int*)d_in[1];
    const int*   edge_dst    = (const int*)d_in[2];
    const float* edge_weight = (const float*)d_in[3];
    const float* w           = (const float*)d_in[4];
    const float* b           = (const float*)d_in[5];
    float* out = (float*)d_out;
    float* h   = (float*)d_ws;                     // 100000*128*4 = 51.2 MB scratch

    init_out_kernel<<<(N_NODES * OUT_F / 4 + 255) / 256, 256, 0, stream>>>(out, b);
    gemm_kernel<<<(N_NODES + 7) / 8, 256, 0, stream>>>(x, w, h);
    scatter_kernel<<<(N_EDGES * 32 + 255) / 256, 256, 0, stream>>>(
        h, edge_src, edge_dst, edge_weight, out);
}

// Round 2
// 820.433 us; speedup vs baseline: 3.8938x; 3.8938x over previous
//
#include <hip/hip_runtime.h>

#define N_NODES 100000
#define N_EDGES 1600000
#define IN_F 256
#define OUT_F 128

#define SCAN_BLOCKS ((N_NODES + 255) / 256)   // 391

// ---------- CSR build ----------

__global__ __launch_bounds__(256) void zero_degcur_kernel(int* __restrict__ degcur) {
    int i = blockIdx.x * 256 + threadIdx.x;
    if (i < N_NODES) degcur[i] = 0;
}

__global__ __launch_bounds__(256) void hist_kernel(const int* __restrict__ edge_dst,
                                                   int* __restrict__ degcur) {
    int e = blockIdx.x * 256 + threadIdx.x;
    if (e < N_EDGES) atomicAdd(&degcur[edge_dst[e]], 1);
}

// Per-block sums of degcur -> blocksum[SCAN_BLOCKS]
__global__ __launch_bounds__(256) void scan1_kernel(const int* __restrict__ degcur,
                                                    int* __restrict__ blocksum) {
    __shared__ int s[256];
    int i = blockIdx.x * 256 + threadIdx.x;
    s[threadIdx.x] = (i < N_NODES) ? degcur[i] : 0;
    __syncthreads();
    for (int st = 128; st > 0; st >>= 1) {
        if (threadIdx.x < st) s[threadIdx.x] += s[threadIdx.x + st];
        __syncthreads();
    }
    if (threadIdx.x == 0) blocksum[blockIdx.x] = s[0];
}

// Exclusive scan of blocksum in-place (single block, 512 threads >= 391)
__global__ __launch_bounds__(512) void scan2_kernel(int* __restrict__ blocksum) {
    __shared__ int s[512];
    int t = threadIdx.x;
    int v = (t < SCAN_BLOCKS) ? blocksum[t] : 0;
    s[t] = v;
    __syncthreads();
    for (int st = 1; st < 512; st <<= 1) {
        int x = (t >= st) ? s[t - st] : 0;
        __syncthreads();
        s[t] += x;
        __syncthreads();
    }
    if (t < SCAN_BLOCKS) blocksum[t] = s[t] - v;   // exclusive
}

// Per-element exclusive scan + block offset -> rowptr; reset degcur to cursor start.
__global__ __launch_bounds__(256) void scan3_kernel(int* __restrict__ degcur,
                                                    const int* __restrict__ blocksum,
                                                    int* __restrict__ rowptr) {
    __shared__ int s[256];
    int t = threadIdx.x;
    int i = blockIdx.x * 256 + t;
    int v = (i < N_NODES) ? degcur[i] : 0;
    s[t] = v;
    __syncthreads();
    for (int st = 1; st < 256; st <<= 1) {
        int x = (t >= st) ? s[t - st] : 0;
        __syncthreads();
        s[t] += x;
        __syncthreads();
    }
    int excl = s[t] - v + blocksum[blockIdx.x];
    if (i < N_NODES) {
        rowptr[i] = excl;
        degcur[i] = excl;   // becomes the fill cursor
    }
    if (i == 0) rowptr[N_NODES] = N_EDGES;
}

// Bucket fill: csr[pos] = (src, bits(weight))
__global__ __launch_bounds__(256) void fill_kernel(const int* __restrict__ edge_src,
                                                   const int* __restrict__ edge_dst,
                                                   const float* __restrict__ edge_weight,
                                                   int* __restrict__ degcur,
                                                   int2* __restrict__ csr) {
    int e = blockIdx.x * 256 + threadIdx.x;
    if (e < N_EDGES) {
        int d = edge_dst[e];
        int pos = atomicAdd(&degcur[d], 1);
        csr[pos] = make_int2(edge_src[e], __float_as_int(edge_weight[e]));
    }
}

// ---------- dense transform (unchanged from R1) ----------

__global__ __launch_bounds__(256) void gemm_kernel(const float* __restrict__ x,
                                                   const float* __restrict__ w,
                                                   float* __restrict__ h) {
    __shared__ float xs[8][IN_F];
    const int block_row = blockIdx.x * 8;
    const int t = threadIdx.x;

    const int nrows = min(8, N_NODES - block_row);
    const int valid4 = nrows * (IN_F / 4);
    const float4* x4 = (const float4*)(x + (long long)block_row * IN_F);
    float4* xs4 = (float4*)&xs[0][0];
    for (int idx = t; idx < 512; idx += 256) {
        if (idx < valid4) xs4[idx] = x4[idx];
    }
    __syncthreads();

    const int r  = t >> 5;
    const int c4 = t & 31;
    float4 acc = make_float4(0.f, 0.f, 0.f, 0.f);
    const float4* w4 = (const float4*)w;
    #pragma unroll 8
    for (int k = 0; k < IN_F; ++k) {
        const float xv = xs[r][k];
        const float4 wv = w4[k * 32 + c4];
        acc.x += xv * wv.x;
        acc.y += xv * wv.y;
        acc.z += xv * wv.z;
        acc.w += xv * wv.w;
    }
    const int row = block_row + r;
    if (row < N_NODES) {
        float4* h4 = (float4*)h;
        h4[(long long)row * 32 + c4] = acc;
    }
}

// ---------- gather-accumulate: out[node] = b + sum_e w_e * h[src_e] ----------
// 8 nodes per 256-block, 32 lanes per node, float4 per lane. No atomics.

__global__ __launch_bounds__(256) void gather_kernel(const float* __restrict__ h,
                                                     const int* __restrict__ rowptr,
                                                     const int2* __restrict__ csr,
                                                     const float* __restrict__ b,
                                                     float* __restrict__ out) {
    const int t = threadIdx.x;
    const int node = blockIdx.x * 8 + (t >> 5);   // N_NODES % 8 == 0
    const int j = t & 31;

    const int start = rowptr[node];
    const int end   = rowptr[node + 1];

    float4 acc = ((const float4*)b)[j];
    const float4* h4 = (const float4*)h;

    for (int p = start; p < end; ++p) {
        int2 sw = csr[p];
        float wgt = __int_as_float(sw.y);
        float4 hv = h4[(long long)sw.x * 32 + j];
        acc.x += wgt * hv.x;
        acc.y += wgt * hv.y;
        acc.z += wgt * hv.z;
        acc.w += wgt * hv.w;
    }
    ((float4*)out)[(long long)node * 32 + j] = acc;
}

extern "C" void kernel_launch(void* const* d_in, const int* in_sizes, int n_in,
                              void* d_out, int out_size, void* d_ws, size_t ws_size,
                              hipStream_t stream) {
    const float* x           = (const float*)d_in[0];
    const int*   edge_src    = (const int*)d_in[1];
    const int*   edge_dst    = (const int*)d_in[2];
    const float* edge_weight = (const float*)d_in[3];
    const float* w           = (const float*)d_in[4];
    const float* b           = (const float*)d_in[5];
    float* out = (float*)d_out;

    // workspace layout (16B-aligned slices), total ~64.8 MB
    char* ws = (char*)d_ws;
    size_t off = 0;
    float* h = (float*)(ws + off);           off += (size_t)N_NODES * OUT_F * 4;     // 51.2 MB
    int* rowptr = (int*)(ws + off);          off += ((size_t)N_NODES + 4) * 4;       // 400 KB
    off = (off + 15) & ~(size_t)15;
    int* degcur = (int*)(ws + off);          off += (size_t)N_NODES * 4;             // 400 KB
    off = (off + 15) & ~(size_t)15;
    int* blocksum = (int*)(ws + off);        off += (size_t)SCAN_BLOCKS * 4;
    off = (off + 15) & ~(size_t)15;
    int2* csr = (int2*)(ws + off);           off += (size_t)N_EDGES * 8;             // 12.8 MB

    const int EB = (N_EDGES + 255) / 256;    // 6250

    zero_degcur_kernel<<<SCAN_BLOCKS, 256, 0, stream>>>(degcur);
    hist_kernel<<<EB, 256, 0, stream>>>(edge_dst, degcur);
    scan1_kernel<<<SCAN_BLOCKS, 256, 0, stream>>>(degcur, blocksum);
    scan2_kernel<<<1, 512, 0, stream>>>(blocksum);
    scan3_kernel<<<SCAN_BLOCKS, 256, 0, stream>>>(degcur, blocksum, rowptr);
    fill_kernel<<<EB, 256, 0, stream>>>(edge_src, edge_dst, edge_weight, degcur, csr);
    gemm_kernel<<<(N_NODES + 7) / 8, 256, 0, stream>>>(x, w, h);
    gather_kernel<<<N_NODES / 8, 256, 0, stream>>>(h, rowptr, csr, b, out);
}

// Round 3
// 476.330 us; speedup vs baseline: 6.7066x; 1.7224x over previous
//
#include <hip/hip_runtime.h>

#define N_NODES 100000
#define N_EDGES 1600000
#define IN_F 256
#define OUT_F 128

#define SCAN_BLOCKS ((N_NODES + 255) / 256)   // 391

typedef __attribute__((ext_vector_type(8))) short bf16x8;
typedef __attribute__((ext_vector_type(4))) float f32x4;

static __device__ __forceinline__ short f2bf(float f) {
    unsigned u = __float_as_uint(f);
    u = (u + 0x7FFFu + ((u >> 16) & 1u)) >> 16;     // RNE; inputs are finite
    return (short)u;
}
static __device__ __forceinline__ float bf2f(short s) {
    return __uint_as_float(((unsigned)(unsigned short)s) << 16);
}

// ---------- CSR build ----------

__global__ __launch_bounds__(256) void zero_degcur_kernel(int* __restrict__ degcur) {
    int i = blockIdx.x * 256 + threadIdx.x;
    if (i < N_NODES) degcur[i] = 0;
}

__global__ __launch_bounds__(256) void hist_kernel(const int* __restrict__ edge_dst,
                                                   int* __restrict__ degcur) {
    int e = blockIdx.x * 256 + threadIdx.x;
    if (e < N_EDGES) atomicAdd(&degcur[edge_dst[e]], 1);
}

__global__ __launch_bounds__(256) void scan1_kernel(const int* __restrict__ degcur,
                                                    int* __restrict__ blocksum) {
    __shared__ int s[256];
    int i = blockIdx.x * 256 + threadIdx.x;
    s[threadIdx.x] = (i < N_NODES) ? degcur[i] : 0;
    __syncthreads();
    for (int st = 128; st > 0; st >>= 1) {
        if (threadIdx.x < st) s[threadIdx.x] += s[threadIdx.x + st];
        __syncthreads();
    }
    if (threadIdx.x == 0) blocksum[blockIdx.x] = s[0];
}

__global__ __launch_bounds__(512) void scan2_kernel(int* __restrict__ blocksum) {
    __shared__ int s[512];
    int t = threadIdx.x;
    int v = (t < SCAN_BLOCKS) ? blocksum[t] : 0;
    s[t] = v;
    __syncthreads();
    for (int st = 1; st < 512; st <<= 1) {
        int x = (t >= st) ? s[t - st] : 0;
        __syncthreads();
        s[t] += x;
        __syncthreads();
    }
    if (t < SCAN_BLOCKS) blocksum[t] = s[t] - v;   // exclusive
}

__global__ __launch_bounds__(256) void scan3_kernel(int* __restrict__ degcur,
                                                    const int* __restrict__ blocksum,
                                                    int* __restrict__ rowptr) {
    __shared__ int s[256];
    int t = threadIdx.x;
    int i = blockIdx.x * 256 + t;
    int v = (i < N_NODES) ? degcur[i] : 0;
    s[t] = v;
    __syncthreads();
    for (int st = 1; st < 256; st <<= 1) {
        int x = (t >= st) ? s[t - st] : 0;
        __syncthreads();
        s[t] += x;
        __syncthreads();
    }
    int excl = s[t] - v + blocksum[blockIdx.x];
    if (i < N_NODES) {
        rowptr[i] = excl;
        degcur[i] = excl;   // becomes the fill cursor
    }
    if (i == 0) rowptr[N_NODES] = N_EDGES;
}

__global__ __launch_bounds__(256) void fill_kernel(const int* __restrict__ edge_src,
                                                   const int* __restrict__ edge_dst,
                                                   const float* __restrict__ edge_weight,
                                                   int* __restrict__ degcur,
                                                   int2* __restrict__ csr) {
    int e = blockIdx.x * 256 + threadIdx.x;
    if (e < N_EDGES) {
        int d = edge_dst[e];
        int pos = atomicAdd(&degcur[d], 1);
        csr[pos] = make_int2(edge_src[e], __float_as_int(edge_weight[e]));
    }
}

// ---------- w transpose + convert: wt[n][k] = bf16(w[k][n]), [128][256] ----------

__global__ __launch_bounds__(256) void wprep_kernel(const float* __restrict__ w,
                                                    unsigned short* __restrict__ wt) {
    int idx = blockIdx.x * 256 + threadIdx.x;       // 32768 total
    int n = idx >> 8;                               // 0..127
    int k = idx & 255;                              // 0..255
    wt[idx] = (unsigned short)f2bf(w[k * OUT_F + n]);
}

// ---------- bf16 MFMA GEMM: h_bf16 = bf16(x) @ bf16(w) ----------
// Block = 256 thr = 4 waves; wave computes 16 rows x 128 cols via 8 C-frags.
// A-frag: lane(m=lane&15,quad=lane>>4) holds x[row][ks*32+quad*8 ..+7] (cvt fp32->bf16)
// B-frag: lane holds wt[nt*16 + m][ks*32+quad*8 ..+7]  (wt = W^T)
// C/D   : col = lane&15, row = quad*4 + reg   [verified m89]

__global__ __launch_bounds__(256) void gemm_mfma_kernel(const float* __restrict__ x,
                                                        const unsigned short* __restrict__ wt,
                                                        unsigned short* __restrict__ hb) {
    const int t = threadIdx.x;
    const int wave = t >> 6;
    const int lane = t & 63;
    const int m = lane & 15;
    const int quad = lane >> 4;

    const int tile_base = blockIdx.x * 64 + wave * 16;
    const int row = tile_base + m;
    const int arow = (row < N_NODES) ? row : (N_NODES - 1);   // clamp; tail rows not stored
    const float* xr = x + (size_t)arow * IN_F;

    f32x4 acc[8];
    #pragma unroll
    for (int nt = 0; nt < 8; ++nt) acc[nt] = (f32x4){0.f, 0.f, 0.f, 0.f};

    #pragma unroll
    for (int ks = 0; ks < 8; ++ks) {
        const float4 a0 = *(const float4*)(xr + ks * 32 + quad * 8);
        const float4 a1 = *(const float4*)(xr + ks * 32 + quad * 8 + 4);
        bf16x8 af;
        af[0] = f2bf(a0.x); af[1] = f2bf(a0.y); af[2] = f2bf(a0.z); af[3] = f2bf(a0.w);
        af[4] = f2bf(a1.x); af[5] = f2bf(a1.y); af[6] = f2bf(a1.z); af[7] = f2bf(a1.w);
        #pragma unroll
        for (int nt = 0; nt < 8; ++nt) {
            const bf16x8 bf = *(const bf16x8*)(wt + (size_t)(nt * 16 + m) * IN_F + ks * 32 + quad * 8);
            acc[nt] = __builtin_amdgcn_mfma_f32_16x16x32_bf16(af, bf, acc[nt], 0, 0, 0);
        }
    }

    #pragma unroll
    for (int nt = 0; nt < 8; ++nt) {
        #pragma unroll
        for (int r = 0; r < 4; ++r) {
            const int orow = tile_base + quad * 4 + r;
            if (orow < N_NODES)
                hb[(size_t)orow * OUT_F + nt * 16 + m] = (unsigned short)f2bf(acc[nt][r]);
        }
    }
}

// ---------- gather: out[node] = b + sum_e w_e * h[src_e] ; h in bf16 ----------
// 16 lanes per node, lane j owns features [j*8, j*8+8). 16 nodes per block.

__global__ __launch_bounds__(256) void gather_kernel(const unsigned short* __restrict__ hb,
                                                     const int* __restrict__ rowptr,
                                                     const int2* __restrict__ csr,
                                                     const float* __restrict__ b,
                                                     float* __restrict__ out) {
    const int t = threadIdx.x;
    const int node = blockIdx.x * 16 + (t >> 4);   // N_NODES % 16 == 0
    const int j = t & 15;

    const int start = rowptr[node];
    const int end   = rowptr[node + 1];

    const float4* b4 = (const float4*)b;
    float4 acc0 = b4[j * 2];
    float4 acc1 = b4[j * 2 + 1];

    for (int p = start; p < end; ++p) {
        const int2 sw = csr[p];
        const float wgt = __int_as_float(sw.y);
        const bf16x8 hv = *(const bf16x8*)(hb + (size_t)sw.x * OUT_F + j * 8);
        acc0.x += wgt * bf2f(hv[0]);
        acc0.y += wgt * bf2f(hv[1]);
        acc0.z += wgt * bf2f(hv[2]);
        acc0.w += wgt * bf2f(hv[3]);
        acc1.x += wgt * bf2f(hv[4]);
        acc1.y += wgt * bf2f(hv[5]);
        acc1.z += wgt * bf2f(hv[6]);
        acc1.w += wgt * bf2f(hv[7]);
    }
    float4* o4 = (float4*)(out + (size_t)node * OUT_F + j * 8);
    o4[0] = acc0;
    o4[1] = acc1;
}

extern "C" void kernel_launch(void* const* d_in, const int* in_sizes, int n_in,
                              void* d_out, int out_size, void* d_ws, size_t ws_size,
                              hipStream_t stream) {
    const float* x           = (const float*)d_in[0];
    const int*   edge_src    = (const int*)d_in[1];
    const int*   edge_dst    = (const int*)d_in[2];
    const float* edge_weight = (const float*)d_in[3];
    const float* w           = (const float*)d_in[4];
    const float* b           = (const float*)d_in[5];
    float* out = (float*)d_out;

    // workspace layout (16B-aligned slices), total ~40 MB
    char* ws = (char*)d_ws;
    size_t off = 0;
    unsigned short* hb = (unsigned short*)(ws + off); off += (size_t)N_NODES * OUT_F * 2;  // 25.6 MB
    unsigned short* wt = (unsigned short*)(ws + off); off += (size_t)IN_F * OUT_F * 2;     // 64 KB
    int* rowptr = (int*)(ws + off);          off += ((size_t)N_NODES + 4) * 4;
    off = (off + 15) & ~(size_t)15;
    int* degcur = (int*)(ws + off);          off += (size_t)N_NODES * 4;
    off = (off + 15) & ~(size_t)15;
    int* blocksum = (int*)(ws + off);        off += (size_t)SCAN_BLOCKS * 4;
    off = (off + 15) & ~(size_t)15;
    int2* csr = (int2*)(ws + off);           off += (size_t)N_EDGES * 8;                   // 12.8 MB

    const int EB = (N_EDGES + 255) / 256;    // 6250

    zero_degcur_kernel<<<SCAN_BLOCKS, 256, 0, stream>>>(degcur);
    hist_kernel<<<EB, 256, 0, stream>>>(edge_dst, degcur);
    scan1_kernel<<<SCAN_BLOCKS, 256, 0, stream>>>(degcur, blocksum);
    scan2_kernel<<<1, 512, 0, stream>>>(blocksum);
    scan3_kernel<<<SCAN_BLOCKS, 256, 0, stream>>>(degcur, blocksum, rowptr);
    fill_kernel<<<EB, 256, 0, stream>>>(edge_src, edge_dst, edge_weight, degcur, csr);
    wprep_kernel<<<(IN_F * OUT_F + 255) / 256, 256, 0, stream>>>(w, wt);
    gemm_mfma_kernel<<<(N_NODES + 63) / 64, 256, 0, stream>>>(x, wt, hb);
    gather_kernel<<<N_NODES / 16, 256, 0, stream>>>(hb, rowptr, csr, b, out);
}

// Round 4
// 473.934 us; speedup vs baseline: 6.7406x; 1.0051x over previous
//
#include <hip/hip_runtime.h>

#define N_NODES 100000
#define N_EDGES 1600000
#define IN_F 256
#define OUT_F 128

#define NBUCK 1563              // ceil(N_NODES / 64)
#define NCELL (NBUCK * 8)       // 12504 (bucket, blockIdx&7) cells
#define CAP 2048                // LDS edge-list capacity; bucket mean=1024, sd=32

typedef __attribute__((ext_vector_type(8))) short bf16x8;
typedef __attribute__((ext_vector_type(4))) float f32x4;

static __device__ __forceinline__ short f2bf(float f) {
    unsigned u = __float_as_uint(f);
    u = (u + 0x7FFFu + ((u >> 16) & 1u)) >> 16;     // RNE; inputs are finite
    return (short)u;
}
static __device__ __forceinline__ float bf2f(short s) {
    return __uint_as_float(((unsigned)(unsigned short)s) << 16);
}

// ---------- coarse partition build ----------

__global__ __launch_bounds__(256) void zero_ccount_kernel(int* __restrict__ ccount) {
    int i = blockIdx.x * 256 + threadIdx.x;
    if (i < NCELL) ccount[i] = 0;
}

// cell = (dst>>6)*8 + (blockIdx&7). Same edge->block mapping as partition_kernel.
__global__ __launch_bounds__(256) void hist8_kernel(const int* __restrict__ edge_dst,
                                                    int* __restrict__ ccount) {
    int e = blockIdx.x * 256 + threadIdx.x;
    if (e < N_EDGES)
        atomicAdd(&ccount[(edge_dst[e] >> 6) * 8 + (blockIdx.x & 7)], 1);
}

// Single-block exclusive scan of NCELL counters -> cscan (+sentinel), ccur copy.
__global__ __launch_bounds__(256) void cscan_kernel(const int* __restrict__ ccount,
                                                    int* __restrict__ cscan,
                                                    int* __restrict__ ccur) {
    __shared__ int ps[256];
    const int t = threadIdx.x;
    const int chunk = (NCELL + 255) / 256;          // 49
    const int base = t * chunk;
    int sum = 0;
    for (int i = 0; i < chunk; ++i) {
        int idx = base + i;
        if (idx < NCELL) sum += ccount[idx];
    }
    ps[t] = sum;
    __syncthreads();
    for (int st = 1; st < 256; st <<= 1) {
        int v = (t >= st) ? ps[t - st] : 0;
        __syncthreads();
        ps[t] += v;
        __syncthreads();
    }
    int run = ps[t] - sum;                          // exclusive block offset
    for (int i = 0; i < chunk; ++i) {
        int idx = base + i;
        if (idx < NCELL) {
            cscan[idx] = run;
            ccur[idx]  = run;
            run += ccount[idx];
        }
    }
    if (t == 0) cscan[NCELL] = N_EDGES;
}

// part[pos] = (src | dst_local<<24, weight_bits); pos from per-(bucket,sub) cursor.
// Sub-cursor = blockIdx&7 ~ XCD id (round-robin dispatch) keeps each write
// stream XCD-private -> dense line fills, ~1x write amplification.
__global__ __launch_bounds__(256) void partition_kernel(const int* __restrict__ edge_src,
                                                        const int* __restrict__ edge_dst,
                                                        const float* __restrict__ edge_weight,
                                                        int* __restrict__ ccur,
                                                        int2* __restrict__ part) {
    int e = blockIdx.x * 256 + threadIdx.x;
    if (e < N_EDGES) {
        int d = edge_dst[e];
        int pos = atomicAdd(&ccur[(d >> 6) * 8 + (blockIdx.x & 7)], 1);
        part[pos] = make_int2(edge_src[e] | ((d & 63) << 24),
                              __float_as_int(edge_weight[e]));
    }
}

// ---------- w transpose + convert: wt[n][k] = bf16(w[k][n]) ----------

__global__ __launch_bounds__(256) void wprep_kernel(const float* __restrict__ w,
                                                    unsigned short* __restrict__ wt) {
    int idx = blockIdx.x * 256 + threadIdx.x;
    int n = idx >> 8;
    int k = idx & 255;
    wt[idx] = (unsigned short)f2bf(w[k * OUT_F + n]);
}

// ---------- bf16 MFMA GEMM (unchanged from R3) ----------

__global__ __launch_bounds__(256) void gemm_mfma_kernel(const float* __restrict__ x,
                                                        const unsigned short* __restrict__ wt,
                                                        unsigned short* __restrict__ hb) {
    const int t = threadIdx.x;
    const int wave = t >> 6;
    const int lane = t & 63;
    const int m = lane & 15;
    const int quad = lane >> 4;

    const int tile_base = blockIdx.x * 64 + wave * 16;
    const int row = tile_base + m;
    const int arow = (row < N_NODES) ? row : (N_NODES - 1);
    const float* xr = x + (size_t)arow * IN_F;

    f32x4 acc[8];
    #pragma unroll
    for (int nt = 0; nt < 8; ++nt) acc[nt] = (f32x4){0.f, 0.f, 0.f, 0.f};

    #pragma unroll
    for (int ks = 0; ks < 8; ++ks) {
        const float4 a0 = *(const float4*)(xr + ks * 32 + quad * 8);
        const float4 a1 = *(const float4*)(xr + ks * 32 + quad * 8 + 4);
        bf16x8 af;
        af[0] = f2bf(a0.x); af[1] = f2bf(a0.y); af[2] = f2bf(a0.z); af[3] = f2bf(a0.w);
        af[4] = f2bf(a1.x); af[5] = f2bf(a1.y); af[6] = f2bf(a1.z); af[7] = f2bf(a1.w);
        #pragma unroll
        for (int nt = 0; nt < 8; ++nt) {
            const bf16x8 bf = *(const bf16x8*)(wt + (size_t)(nt * 16 + m) * IN_F + ks * 32 + quad * 8);
            acc[nt] = __builtin_amdgcn_mfma_f32_16x16x32_bf16(af, bf, acc[nt], 0, 0, 0);
        }
    }

    #pragma unroll
    for (int nt = 0; nt < 8; ++nt) {
        #pragma unroll
        for (int r = 0; r < 4; ++r) {
            const int orow = tile_base + quad * 4 + r;
            if (orow < N_NODES)
                hb[(size_t)orow * OUT_F + nt * 16 + m] = (unsigned short)f2bf(acc[nt][r]);
        }
    }
}

// ---------- fused SpMM: per-bucket LDS binning + gather ----------
// Block = bucket of 64 nodes. Build per-node edge lists in LDS, then
// 16 lanes/node x 4 node-groups gather hb[src] and write out coalesced.

__global__ __launch_bounds__(256) void spmm_kernel(const unsigned short* __restrict__ hb,
                                                   const int* __restrict__ cscan,
                                                   const int2* __restrict__ part,
                                                   const float* __restrict__ b,
                                                   float* __restrict__ out) {
    __shared__ int lh[64];
    __shared__ int lstart[65];
    __shared__ int lcur[64];
    __shared__ int2 list[CAP];

    const int t = threadIdx.x;
    const int base = blockIdx.x * 64;
    const int s = cscan[blockIdx.x * 8];
    const int e = cscan[blockIdx.x * 8 + 8];
    const int cnt = e - s;

    const int j = t & 15;
    const float4* b4 = (const float4*)b;
    const float4 bb0 = b4[j * 2];
    const float4 bb1 = b4[j * 2 + 1];

    if (cnt <= CAP) {
        if (t < 64) lh[t] = 0;
        __syncthreads();
        for (int i = t; i < cnt; i += 256)
            atomicAdd(&lh[((unsigned)part[s + i].x) >> 24], 1);
        __syncthreads();
        if (t == 0) {
            int run = 0;
            for (int n = 0; n < 64; ++n) {
                lstart[n] = run;
                lcur[n] = run;
                run += lh[n];
            }
            lstart[64] = run;
        }
        __syncthreads();
        for (int i = t; i < cnt; i += 256) {
            int2 en = part[s + i];
            int pos = atomicAdd(&lcur[((unsigned)en.x) >> 24], 1);
            list[pos] = make_int2(en.x & 0xFFFFFF, en.y);
        }
        __syncthreads();

        #pragma unroll
        for (int g = 0; g < 4; ++g) {
            const int n = g * 16 + (t >> 4);
            const int node = base + n;
            if (node >= N_NODES) continue;
            float4 acc0 = bb0, acc1 = bb1;
            const int p1 = lstart[n + 1];
            for (int p = lstart[n]; p < p1; ++p) {
                const int2 sw = list[p];
                const float wgt = __int_as_float(sw.y);
                const bf16x8 hv = *(const bf16x8*)(hb + (size_t)sw.x * OUT_F + j * 8);
                acc0.x += wgt * bf2f(hv[0]);
                acc0.y += wgt * bf2f(hv[1]);
                acc0.z += wgt * bf2f(hv[2]);
                acc0.w += wgt * bf2f(hv[3]);
                acc1.x += wgt * bf2f(hv[4]);
                acc1.y += wgt * bf2f(hv[5]);
                acc1.z += wgt * bf2f(hv[6]);
                acc1.w += wgt * bf2f(hv[7]);
            }
            float4* o4 = (float4*)(out + (size_t)node * OUT_F + j * 8);
            o4[0] = acc0;
            o4[1] = acc1;
        }
    } else {
        // overflow fallback (statistically unreachable): filter-scan global part
        for (int g = 0; g < 4; ++g) {
            const int n = g * 16 + (t >> 4);
            const int node = base + n;
            if (node >= N_NODES) continue;
            float4 acc0 = bb0, acc1 = bb1;
            for (int p = 0; p < cnt; ++p) {
                const int2 sw = part[s + p];
                if ((int)(((unsigned)sw.x) >> 24) != n) continue;
                const float wgt = __int_as_float(sw.y);
                const bf16x8 hv = *(const bf16x8*)(hb + (size_t)(sw.x & 0xFFFFFF) * OUT_F + j * 8);
                acc0.x += wgt * bf2f(hv[0]);
                acc0.y += wgt * bf2f(hv[1]);
                acc0.z += wgt * bf2f(hv[2]);
                acc0.w += wgt * bf2f(hv[3]);
                acc1.x += wgt * bf2f(hv[4]);
                acc1.y += wgt * bf2f(hv[5]);
                acc1.z += wgt * bf2f(hv[6]);
                acc1.w += wgt * bf2f(hv[7]);
            }
            float4* o4 = (float4*)(out + (size_t)node * OUT_F + j * 8);
            o4[0] = acc0;
            o4[1] = acc1;
        }
    }
}

extern "C" void kernel_launch(void* const* d_in, const int* in_sizes, int n_in,
                              void* d_out, int out_size, void* d_ws, size_t ws_size,
                              hipStream_t stream) {
    const float* x           = (const float*)d_in[0];
    const int*   edge_src    = (const int*)d_in[1];
    const int*   edge_dst    = (const int*)d_in[2];
    const float* edge_weight = (const float*)d_in[3];
    const float* w           = (const float*)d_in[4];
    const float* b           = (const float*)d_in[5];
    float* out = (float*)d_out;

    // workspace layout (16B-aligned slices), total ~38.6 MB
    char* ws = (char*)d_ws;
    size_t off = 0;
    unsigned short* hb = (unsigned short*)(ws + off); off += (size_t)N_NODES * OUT_F * 2;  // 25.6 MB
    unsigned short* wt = (unsigned short*)(ws + off); off += (size_t)IN_F * OUT_F * 2;     // 64 KB
    int* ccount = (int*)(ws + off);          off += (size_t)NCELL * 4;
    off = (off + 15) & ~(size_t)15;
    int* cscan = (int*)(ws + off);           off += ((size_t)NCELL + 4) * 4;
    off = (off + 15) & ~(size_t)15;
    int* ccur = (int*)(ws + off);            off += (size_t)NCELL * 4;
    off = (off + 15) & ~(size_t)15;
    int2* part = (int2*)(ws + off);          off += (size_t)N_EDGES * 8;                   // 12.8 MB

    const int EB = (N_EDGES + 255) / 256;    // 6250

    zero_ccount_kernel<<<(NCELL + 255) / 256, 256, 0, stream>>>(ccount);
    hist8_kernel<<<EB, 256, 0, stream>>>(edge_dst, ccount);
    cscan_kernel<<<1, 256, 0, stream>>>(ccount, cscan, ccur);
    partition_kernel<<<EB, 256, 0, stream>>>(edge_src, edge_dst, edge_weight, ccur, part);
    wprep_kernel<<<(IN_F * OUT_F + 255) / 256, 256, 0, stream>>>(w, wt);
    gemm_mfma_kernel<<<(N_NODES + 63) / 64, 256, 0, stream>>>(x, wt, hb);
    spmm_kernel<<<NBUCK, 256, 0, stream>>>(hb, cscan, part, b, out);
}

// Round 5
// 347.402 us; speedup vs baseline: 9.1956x; 1.3642x over previous
//
#include <hip/hip_runtime.h>

#define N_NODES 100000
#define N_EDGES 1600000
#define IN_F 256
#define OUT_F 128

#define NBUCK 1563              // ceil(N_NODES / 64)
#define SUB 8
#define NCELL (NBUCK * SUB)     // 12504
#define CELL_CAP 256            // per-cell slots; cell mean=128, sd=11.3
#define LIST_CAP (SUB * CELL_CAP)   // 2048 per bucket
#define SPILL_CAP 65536

typedef __attribute__((ext_vector_type(8))) short bf16x8;
typedef __attribute__((ext_vector_type(4))) float f32x4;

static __device__ __forceinline__ unsigned f2bf_u(float f) {
    unsigned u = __float_as_uint(f);
    return (u + 0x7FFFu + ((u >> 16) & 1u)) >> 16;      // RNE; inputs finite
}
static __device__ __forceinline__ float bf2f(short s) {
    return __uint_as_float(((unsigned)(unsigned short)s) << 16);
}

// ---------- zero counters (cnt[NCELL] + spill_cnt) ----------
__global__ __launch_bounds__(256) void zero_cnt_kernel(int* __restrict__ cnt) {
    int i = blockIdx.x * 256 + threadIdx.x;
    if (i < NCELL + 1) cnt[i] = 0;                       // cnt[NCELL] = spill counter
}

// ---------- direct fixed-capacity partition (no pre-scan) ----------
// cell = (dst>>6)*8 + (blockIdx&7); blockIdx&7 ~ XCD id keeps write streams local.
__global__ __launch_bounds__(256) void partition_kernel(const int* __restrict__ edge_src,
                                                        const int* __restrict__ edge_dst,
                                                        const float* __restrict__ edge_weight,
                                                        int* __restrict__ cnt,
                                                        int2* __restrict__ part,
                                                        int4* __restrict__ spill) {
    int e = blockIdx.x * 256 + threadIdx.x;
    if (e < N_EDGES) {
        int d = edge_dst[e];
        int cell = (d >> 6) * SUB + (blockIdx.x & 7);
        int pos = atomicAdd(&cnt[cell], 1);
        if (pos < CELL_CAP) {
            part[(size_t)cell * CELL_CAP + pos] =
                make_int2(edge_src[e] | ((d & 63) << 24), __float_as_int(edge_weight[e]));
        } else {                                          // statistically unreachable
            int sp = atomicAdd(&cnt[NCELL], 1);
            if (sp < SPILL_CAP)
                spill[sp] = make_int4(edge_src[e], d, __float_as_int(edge_weight[e]), 0);
        }
    }
}

// ---------- wt -> bf16 fragment-major: frag(ks,nt), lane(m,q) ----------
// wtf[(ks*8+nt)*512 + lane*8 + j] = bf16(w[(ks*32+q*8+j)*128 + nt*16+m])
__global__ __launch_bounds__(256) void wprep_kernel(const float* __restrict__ w,
                                                    unsigned short* __restrict__ wtf) {
    int id = blockIdx.x * 256 + threadIdx.x;             // 4096 = 64 frags x 64 lanes
    if (id >= 4096) return;
    int f = id >> 6, lane = id & 63;
    int ks = f >> 3, nt = f & 7;
    int m = lane & 15, q = lane >> 4;
    int row = nt * 16 + m;
    int col0 = ks * 32 + q * 8;
    unsigned short* o = wtf + (size_t)f * 512 + lane * 8;
    #pragma unroll
    for (int j = 0; j < 8; ++j)
        o[j] = (unsigned short)f2bf_u(w[(size_t)(col0 + j) * OUT_F + row]);
}

// ---------- MFMA GEMM, LDS-staged x, fragment-major wt ----------
// Block 256 = 4 waves; tile 64 rows. LDS: bf16 x-tile [64][264] = 33.8 KB.
__global__ __launch_bounds__(256) void gemm_mfma_kernel(const float* __restrict__ x,
                                                        const unsigned short* __restrict__ wtf,
                                                        unsigned short* __restrict__ hb) {
    __shared__ unsigned short xs[64][264];               // stride 264: 16B-aligned rows
    const int t = threadIdx.x;
    const int row0 = blockIdx.x * 64;

    // Stage: 64 rows x 256 fp32 -> bf16 LDS, coalesced (4096 float4 / 256 thr).
    const float4* x4 = (const float4*)x;
    #pragma unroll
    for (int i = 0; i < 16; ++i) {
        int idx = t + i * 256;
        int r = idx >> 6, c4 = idx & 63;
        int rg = row0 + r; if (rg >= N_NODES) rg = N_NODES - 1;
        float4 v = x4[(size_t)rg * 64 + c4];
        unsigned u0 = f2bf_u(v.x) | (f2bf_u(v.y) << 16);
        unsigned u1 = f2bf_u(v.z) | (f2bf_u(v.w) << 16);
        *(uint2*)&xs[r][c4 * 4] = make_uint2(u0, u1);
    }
    __syncthreads();

    const int wave = t >> 6, lane = t & 63;
    const int m = lane & 15, quad = lane >> 4;

    // All 8 A-frags up front (ds_read_b128 each).
    bf16x8 af[8];
    #pragma unroll
    for (int ks = 0; ks < 8; ++ks)
        af[ks] = *(const bf16x8*)&xs[wave * 16 + m][ks * 32 + quad * 8];

    f32x4 acc[8];
    #pragma unroll
    for (int nt = 0; nt < 8; ++nt) acc[nt] = (f32x4){0.f, 0.f, 0.f, 0.f};

    const bf16x8* wf = (const bf16x8*)wtf;               // frag-major, coalesced
    #pragma unroll
    for (int ks = 0; ks < 8; ++ks) {
        #pragma unroll
        for (int nt = 0; nt < 8; ++nt) {
            bf16x8 bf = wf[(size_t)(ks * 8 + nt) * 64 + lane];
            acc[nt] = __builtin_amdgcn_mfma_f32_16x16x32_bf16(af[ks], bf, acc[nt], 0, 0, 0);
        }
    }

    const int tile_base = row0 + wave * 16;
    #pragma unroll
    for (int nt = 0; nt < 8; ++nt) {
        #pragma unroll
        for (int r = 0; r < 4; ++r) {
            int orow = tile_base + quad * 4 + r;         // C/D: col=lane&15, row=quad*4+reg
            if (orow < N_NODES)
                hb[(size_t)orow * OUT_F + nt * 16 + m] = (unsigned short)f2bf_u(acc[nt][r]);
        }
    }
}

// ---------- fused SpMM over fixed-slot cells ----------
__global__ __launch_bounds__(256) void spmm_kernel(const unsigned short* __restrict__ hb,
                                                   const int* __restrict__ cnt,
                                                   const int2* __restrict__ part,
                                                   const float* __restrict__ b,
                                                   float* __restrict__ out) {
    __shared__ int lh[64];
    __shared__ int lstart[65];
    __shared__ int lcur[64];
    __shared__ int2 list[LIST_CAP];

    const int t = threadIdx.x;
    const int base = blockIdx.x * 64;

    if (t < 64) lh[t] = 0;
    __syncthreads();

    // Pass 1: read <=1 edge per (thread, sub) into registers; LDS histogram.
    int2 stash[SUB];
    int  sn[SUB];
    int  csub[SUB];
    #pragma unroll
    for (int sub = 0; sub < SUB; ++sub) {
        int cell = blockIdx.x * SUB + sub;
        int c = cnt[cell]; if (c > CELL_CAP) c = CELL_CAP;
        csub[sub] = c;
        sn[sub] = -1;
        if (t < c) {
            int2 en = part[(size_t)cell * CELL_CAP + t];
            int n = ((unsigned)en.x) >> 24;
            stash[sub] = make_int2(en.x & 0xFFFFFF, en.y);
            sn[sub] = n;
            atomicAdd(&lh[n], 1);
        }
    }
    __syncthreads();

    // Wave-0 shuffle exclusive scan of the 64 node counters.
    if (t < 64) {
        int v = lh[t];
        int s = v;
        #pragma unroll
        for (int off = 1; off < 64; off <<= 1) {
            int o = __shfl_up(s, off);
            if (t >= off) s += o;
        }
        lstart[t] = s - v;
        lcur[t]   = s - v;
        if (t == 63) lstart[64] = s;
    }
    __syncthreads();

    // Pass 2: scatter stashed edges into per-node LDS lists.
    #pragma unroll
    for (int sub = 0; sub < SUB; ++sub) {
        if (sn[sub] >= 0) {
            int pos = atomicAdd(&lcur[sn[sub]], 1);
            list[pos] = stash[sub];
        }
    }
    __syncthreads();

    // Gather: 16 lanes per node, 4 node-groups.
    const int j = t & 15;
    const float4* b4 = (const float4*)b;
    const float4 bb0 = b4[j * 2];
    const float4 bb1 = b4[j * 2 + 1];

    #pragma unroll
    for (int g = 0; g < 4; ++g) {
        const int n = g * 16 + (t >> 4);
        const int node = base + n;
        if (node >= N_NODES) continue;
        float4 acc0 = bb0, acc1 = bb1;
        const int p1 = lstart[n + 1];
        for (int p = lstart[n]; p < p1; ++p) {
            const int2 sw = list[p];
            const float wgt = __int_as_float(sw.y);
            const bf16x8 hv = *(const bf16x8*)(hb + (size_t)sw.x * OUT_F + j * 8);
            acc0.x += wgt * bf2f(hv[0]);
            acc0.y += wgt * bf2f(hv[1]);
            acc0.z += wgt * bf2f(hv[2]);
            acc0.w += wgt * bf2f(hv[3]);
            acc1.x += wgt * bf2f(hv[4]);
            acc1.y += wgt * bf2f(hv[5]);
            acc1.z += wgt * bf2f(hv[6]);
            acc1.w += wgt * bf2f(hv[7]);
        }
        float4* o4 = (float4*)(out + (size_t)node * OUT_F + j * 8);
        o4[0] = acc0;
        o4[1] = acc1;
    }
}

// ---------- spill fixup (normally 0 edges; must still launch) ----------
__global__ __launch_bounds__(256) void spill_kernel(const unsigned short* __restrict__ hb,
                                                    const int* __restrict__ cnt,
                                                    const int4* __restrict__ spill,
                                                    float* __restrict__ out) {
    int n = cnt[NCELL]; if (n > SPILL_CAP) n = SPILL_CAP;
    const int total = n * OUT_F;
    for (int idx = blockIdx.x * 256 + threadIdx.x; idx < total; idx += 16384) {
        int e = idx >> 7, f = idx & 127;
        int4 sp = spill[e];
        float v = __int_as_float(sp.z) * bf2f((short)hb[(size_t)sp.x * OUT_F + f]);
        atomicAdd(&out[(size_t)sp.y * OUT_F + f], v);
    }
}

extern "C" void kernel_launch(void* const* d_in, const int* in_sizes, int n_in,
                              void* d_out, int out_size, void* d_ws, size_t ws_size,
                              hipStream_t stream) {
    const float* x           = (const float*)d_in[0];
    const int*   edge_src    = (const int*)d_in[1];
    const int*   edge_dst    = (const int*)d_in[2];
    const float* edge_weight = (const float*)d_in[3];
    const float* w           = (const float*)d_in[4];
    const float* b           = (const float*)d_in[5];
    float* out = (float*)d_out;

    // workspace layout (16B-aligned), total ~52.4 MB
    char* ws = (char*)d_ws;
    size_t off = 0;
    unsigned short* hb  = (unsigned short*)(ws + off); off += (size_t)N_NODES * OUT_F * 2;   // 25.6 MB
    unsigned short* wtf = (unsigned short*)(ws + off); off += (size_t)IN_F * OUT_F * 2;      // 64 KB
    int* cnt = (int*)(ws + off);   off += ((size_t)NCELL + 4) * 4;                           // 50 KB
    off = (off + 15) & ~(size_t)15;
    int4* spill = (int4*)(ws + off); off += (size_t)SPILL_CAP * 16;                          // 1 MB
    int2* part = (int2*)(ws + off);  off += (size_t)NCELL * CELL_CAP * 8;                    // 25.6 MB

    const int EB = (N_EDGES + 255) / 256;    // 6250

    zero_cnt_kernel<<<(NCELL + 256) / 256, 256, 0, stream>>>(cnt);
    partition_kernel<<<EB, 256, 0, stream>>>(edge_src, edge_dst, edge_weight, cnt, part, spill);
    wprep_kernel<<<16, 256, 0, stream>>>(w, wtf);
    gemm_mfma_kernel<<<(N_NODES + 63) / 64, 256, 0, stream>>>(x, wtf, hb);
    spmm_kernel<<<NBUCK, 256, 0, stream>>>(hb, cnt, part, b, out);
    spill_kernel<<<64, 256, 0, stream>>>(hb, cnt, spill, out);
}